// Round 6
// baseline (1220.403 us; speedup 1.0000x reference)
//
#include <hip/hip_runtime.h>
#include <hip/hip_bf16.h>

#define BQ 4
#define SQ 4096
#define DQ 256
#define N3 768
#define KBLK 64
#define NITER (SQ / KBLK)

typedef __attribute__((ext_vector_type(8))) _Float16 f16x8;
typedef __attribute__((ext_vector_type(4))) _Float16 f16x4;
typedef __attribute__((ext_vector_type(4))) float f32x4;
typedef __attribute__((ext_vector_type(4))) unsigned int u32x4;

__device__ __forceinline__ short f2h(float f) {
  _Float16 h = (_Float16)f;
  union { _Float16 h; short s; } v; v.h = h;
  return v.s;
}

__device__ __forceinline__ void gload16(const void* g, void* lds) {
  __builtin_amdgcn_global_load_lds(
      (const __attribute__((address_space(1))) unsigned int*)g,
      (__attribute__((address_space(3))) unsigned int*)lds, 16, 0, 0);
}

// ---------------- QKV projection (unchanged, working) ----------------
__global__ __launch_bounds__(256) void qkv_kernel(
    const float* __restrict__ x, const float* __restrict__ Wqkv,
    const float* __restrict__ bqkv,
    short* __restrict__ Qb, short* __restrict__ Kb, short* __restrict__ Vt) {
  __shared__ short As[64][72];
  __shared__ short Ws[64][72];
  const int t = threadIdx.x;
  const int l = t & 63, w = t >> 6;
  const int lr = l & 15, lg = l >> 4;
  const int Mbase = blockIdx.x * 64;
  const int Nbase = blockIdx.y * 64;

  f32x4 acc[4] = {};
  for (int kit = 0; kit < 4; ++kit) {
    const int k0 = kit * 64;
    {
      const int m = t >> 2, kc = (t & 3) * 16;
      const float* src = x + (size_t)(Mbase + m) * DQ + k0 + kc;
      short tmp[16];
#pragma unroll
      for (int i = 0; i < 16; ++i) tmp[i] = f2h(src[i]);
      *(u32x4*)&As[m][kc] = *(u32x4*)&tmp[0];
      *(u32x4*)&As[m][kc + 8] = *(u32x4*)&tmp[8];
    }
    {
      const int n = t & 63, kc2 = (t >> 6) * 16;
      short tmp[16];
#pragma unroll
      for (int i = 0; i < 16; ++i)
        tmp[i] = f2h(Wqkv[(size_t)(k0 + kc2 + i) * N3 + Nbase + n]);
      *(u32x4*)&Ws[n][kc2] = *(u32x4*)&tmp[0];
      *(u32x4*)&Ws[n][kc2 + 8] = *(u32x4*)&tmp[8];
    }
    __syncthreads();
#pragma unroll
    for (int kk = 0; kk < 2; ++kk) {
      f16x8 af = *(f16x8*)&As[w * 16 + lr][kk * 32 + lg * 8];
#pragma unroll
      for (int nf = 0; nf < 4; ++nf) {
        f16x8 bfr = *(f16x8*)&Ws[nf * 16 + lr][kk * 32 + lg * 8];
        acc[nf] = __builtin_amdgcn_mfma_f32_16x16x32_f16(af, bfr, acc[nf], 0, 0, 0);
      }
    }
    __syncthreads();
  }
#pragma unroll
  for (int nf = 0; nf < 4; ++nf) {
    const int col = Nbase + nf * 16 + lr;
    const float bias = bqkv[col];
#pragma unroll
    for (int r = 0; r < 4; ++r) {
      const int row = Mbase + w * 16 + lg * 4 + r;
      const short sv = f2h(acc[nf][r] + bias);
      if (col < 256) {
        Qb[(size_t)row * DQ + col] = sv;
      } else if (col < 512) {
        Kb[(size_t)row * DQ + (col - 256)] = sv;
      } else {
        const int b = row >> 12, s = row & 4095;
        Vt[(size_t)(b * 256 + (col - 512)) * SQ + s] = sv;
      }
    }
  }
}

// ---------------- Wcomb = Wproj @ Wfc ; c0 = bproj @ Wfc + bfc ----------------
__global__ void wcomb_kernel(const float* __restrict__ Wproj,
                             const float* __restrict__ bproj,
                             const float* __restrict__ Wfc,
                             const float* __restrict__ bfc,
                             float* __restrict__ Wc) {
  __shared__ float wf[256];
  const int t = threadIdx.x;
  wf[t] = Wfc[t];
  __syncthreads();
  float acc = 0.f;
  for (int j = 0; j < 256; ++j) acc += Wproj[(size_t)t * 256 + j] * wf[j];
  Wc[t] = acc;
  if (t == 0) {
    float c = bfc[0];
    for (int j = 0; j < 256; ++j) c += bproj[j] * wf[j];
    Wc[256] = c;
  }
}

// ---------------- Flash attention + fused (proj@fc) epilogue ----------------
// grid 256, 512 threads (8 waves). Block = 64 q-rows. Wave (qg = w>>2, h = w&3):
// 32 q-rows (2 m-tiles) x 16 keys of each 64-key tile. K/V double-buffered in
// LDS via global_load_lds, XOR-swizzled chunks (source ^(row&7), read ^(lr&7)).
// Softmax: defer-max gate (no cross-lane ops in common path), per-lane l_run.
__global__ __launch_bounds__(512, 2) void attn_kernel(
    const short* __restrict__ Qb, const short* __restrict__ Kb,
    const short* __restrict__ Vt, const float* __restrict__ Wc,
    float* __restrict__ out) {
  __shared__ short Ks[2][64][256];   // [buf][key][d]  linear dest, XOR-swz content
  __shared__ short Vs[2][256][64];   // [buf][d][key]  linear dest, XOR-swz content
  __shared__ short Ps[8][32][20];    // per-wave P [qrow][key], pitch 40B
  __shared__ float Mrg[2][4][32][3]; // [qg][h][row]{m,l,part}

  const int t = threadIdx.x;
  const int l = t & 63, w = t >> 6;
  const int lr = l & 15, lg = l >> 4;
  const int qg = w >> 2, h = w & 3;
  const int bid = blockIdx.x;
  const int b = bid & 3;                 // XCD i serves batch i&3 (bid%8 -> XCD)
  const int qbase = (bid >> 2) * 64;

  const short* kbase = Kb + (size_t)b * SQ * DQ;
  const short* vbase = Vt + (size_t)b * DQ * SQ;

  // Q fragments: wave's 32 rows (2 m-tiles) x 256 d
  f16x8 qf[2][8];
#pragma unroll
  for (int mm = 0; mm < 2; ++mm) {
    const short* qptr = Qb + (size_t)(b * SQ + qbase + qg * 32 + mm * 16 + lr) * DQ;
#pragma unroll
    for (int kk = 0; kk < 8; ++kk)
      qf[mm][kk] = *(const f16x8*)(qptr + kk * 32 + lg * 8);
  }

  // stage tile KB into buffer BUF (8 x global_load_lds per wave)
  // K: LDS chunk c of row kr holds global chunk c^(kr&7)  (16B chunks)
  // V: LDS chunk c of row vd holds global chunk c^(vd&7)
#define STAGE(BUF, KB)                                                        \
  {                                                                           \
    _Pragma("unroll") for (int i = 0; i < 4; ++i) {                           \
      const int kr = w * 8 + i * 2 + (l >> 5);                                \
      const int gc = (l & 31) ^ (kr & 7);                                     \
      gload16(kbase + (size_t)((KB)*64 + kr) * DQ + gc * 8,                   \
              &Ks[BUF][w * 8 + i * 2][0]);                                    \
    }                                                                         \
    _Pragma("unroll") for (int i = 0; i < 4; ++i) {                           \
      const int vd = w * 32 + i * 8 + (l >> 3);                               \
      const int gc = (l & 7) ^ (vd & 7);                                      \
      gload16(vbase + (size_t)vd * SQ + (KB)*64 + gc * 8,                     \
              &Vs[BUF][w * 32 + i * 8][0]);                                   \
    }                                                                         \
  }

  f32x4 o[2][16] = {};
  float m_run[2][4], l_run[2][4];
#pragma unroll
  for (int mm = 0; mm < 2; ++mm)
#pragma unroll
    for (int r = 0; r < 4; ++r) { m_run[mm][r] = -1e30f; l_run[mm][r] = 0.f; }

  STAGE(0, 0);
  __syncthreads();  // drains vmcnt -> buf0 ready

  for (int kb = 0; kb < NITER; ++kb) {
    const int cur = kb & 1;
    if (kb + 1 < NITER) STAGE(cur ^ 1, kb + 1);

    // ---- S = Q K^T on this wave's 16 keys (two 4-deep acc chains) ----
    const char* kR = (const char*)&Ks[cur][h * 16 + lr][0];
    f32x4 sA[2] = {}, sB[2] = {};
#pragma unroll
    for (int kk = 0; kk < 4; ++kk) {
      f16x8 kf = *(const f16x8*)(kR + (((4 * kk + lg) ^ (lr & 7)) << 4));
      sA[0] = __builtin_amdgcn_mfma_f32_16x16x32_f16(qf[0][kk], kf, sA[0], 0, 0, 0);
      sA[1] = __builtin_amdgcn_mfma_f32_16x16x32_f16(qf[1][kk], kf, sA[1], 0, 0, 0);
    }
#pragma unroll
    for (int kk = 4; kk < 8; ++kk) {
      f16x8 kf = *(const f16x8*)(kR + (((4 * kk + lg) ^ (lr & 7)) << 4));
      sB[0] = __builtin_amdgcn_mfma_f32_16x16x32_f16(qf[0][kk], kf, sB[0], 0, 0, 0);
      sB[1] = __builtin_amdgcn_mfma_f32_16x16x32_f16(qf[1][kk], kf, sB[1], 0, 0, 0);
    }
    f32x4 s[2];
#pragma unroll
    for (int mm = 0; mm < 2; ++mm)
#pragma unroll
      for (int r = 0; r < 4; ++r) s[mm][r] = sA[mm][r] + sB[mm][r];

    // ---- softmax: defer-max gate; no cross-lane ops in common path ----
    bool over = false;
#pragma unroll
    for (int mm = 0; mm < 2; ++mm)
#pragma unroll
      for (int r = 0; r < 4; ++r) over = over || (s[mm][r] > m_run[mm][r] + 8.f);
    if (__any(over)) {
      float mt[2][4];
#pragma unroll
      for (int mm = 0; mm < 2; ++mm)
#pragma unroll
        for (int r = 0; r < 4; ++r) mt[mm][r] = s[mm][r];
#pragma unroll
      for (int mask = 1; mask <= 8; mask <<= 1)
#pragma unroll
        for (int mm = 0; mm < 2; ++mm)
#pragma unroll
          for (int r = 0; r < 4; ++r)
            mt[mm][r] = fmaxf(mt[mm][r], __shfl_xor(mt[mm][r], mask, 64));
#pragma unroll
      for (int mm = 0; mm < 2; ++mm)
#pragma unroll
        for (int r = 0; r < 4; ++r) {
          const float mn = fmaxf(m_run[mm][r], mt[mm][r]);
          const float sc = __expf(m_run[mm][r] - mn);
          m_run[mm][r] = mn;
          l_run[mm][r] *= sc;
#pragma unroll
          for (int nb = 0; nb < 16; ++nb) o[mm][nb][r] *= sc;
        }
    }
    float p[2][4];
#pragma unroll
    for (int mm = 0; mm < 2; ++mm)
#pragma unroll
      for (int r = 0; r < 4; ++r) {
        p[mm][r] = __expf(s[mm][r] - m_run[mm][r]);  // <= e^8
        l_run[mm][r] += p[mm][r];                    // per-lane partial sum
      }

    // ---- P (C-layout) -> per-wave LDS -> A-frags ----
#pragma unroll
    for (int mm = 0; mm < 2; ++mm)
#pragma unroll
      for (int r = 0; r < 4; ++r)
        Ps[w][mm * 16 + lg * 4 + r][lr] = f2h(p[mm][r]);
    f16x4 pa[2];
#pragma unroll
    for (int mm = 0; mm < 2; ++mm)
      pa[mm] = *(const f16x4*)&Ps[w][mm * 16 + lr][lg * 4];

    // ---- O += P @ V (16x16x16, K=16 keys) ----
#pragma unroll
    for (int nb = 0; nb < 16; ++nb) {
      const int vd = nb * 16 + lr;
      const char* vR = (const char*)&Vs[cur][vd][0];
      f16x4 vf = *(const f16x4*)(vR + (((2 * h + (lg >> 1)) ^ (lr & 7)) << 4) +
                                 (lg & 1) * 8);
      o[0][nb] = __builtin_amdgcn_mfma_f32_16x16x16f16(pa[0], vf, o[0][nb], 0, 0, 0);
      o[1][nb] = __builtin_amdgcn_mfma_f32_16x16x16f16(pa[1], vf, o[1][nb], 0, 0, 0);
    }
    __syncthreads();  // next tile landed (vmcnt drain) + reads of cur done
  }

  // ---- epilogue: part = O . Wcomb slice; reduce part and l over lr lanes ----
  const float c0 = Wc[256];
  float part[2][4] = {};
#pragma unroll
  for (int nb = 0; nb < 16; ++nb) {
    const float wc = Wc[nb * 16 + lr];
#pragma unroll
    for (int mm = 0; mm < 2; ++mm)
#pragma unroll
      for (int r = 0; r < 4; ++r) part[mm][r] += o[mm][nb][r] * wc;
  }
#pragma unroll
  for (int mask = 1; mask <= 8; mask <<= 1)
#pragma unroll
    for (int mm = 0; mm < 2; ++mm)
#pragma unroll
      for (int r = 0; r < 4; ++r) {
        part[mm][r] += __shfl_xor(part[mm][r], mask, 64);
        l_run[mm][r] += __shfl_xor(l_run[mm][r], mask, 64);
      }

  if (lr == 0) {
#pragma unroll
    for (int mm = 0; mm < 2; ++mm)
#pragma unroll
      for (int r = 0; r < 4; ++r) {
        const int row = mm * 16 + lg * 4 + r;
        Mrg[qg][h][row][0] = m_run[mm][r];
        Mrg[qg][h][row][1] = l_run[mm][r];
        Mrg[qg][h][row][2] = part[mm][r];
      }
  }
  __syncthreads();

  if (h == 0 && l < 32) {
    const int row = l;
    float M = Mrg[qg][0][row][0];
#pragma unroll
    for (int hh = 1; hh < 4; ++hh) M = fmaxf(M, Mrg[qg][hh][row][0]);
    float lt = 0.f, pt = 0.f;
#pragma unroll
    for (int hh = 0; hh < 4; ++hh) {
      const float e = __expf(Mrg[qg][hh][row][0] - M);
      lt += e * Mrg[qg][hh][row][1];
      pt += e * Mrg[qg][hh][row][2];
    }
    out[(size_t)b * SQ + qbase + qg * 32 + row] = pt / lt + c0;
  }
#undef STAGE
}

// ---------------- launch ----------------
extern "C" void kernel_launch(void* const* d_in, const int* in_sizes, int n_in,
                              void* d_out, int out_size, void* d_ws, size_t ws_size,
                              hipStream_t stream) {
  const float* x     = (const float*)d_in[0];
  const float* Wqkv  = (const float*)d_in[1];
  const float* bqkv  = (const float*)d_in[2];
  const float* Wproj = (const float*)d_in[3];
  const float* bproj = (const float*)d_in[4];
  const float* Wfc   = (const float*)d_in[5];
  const float* bfc   = (const float*)d_in[6];
  float* out = (float*)d_out;

  const size_t SEG = (size_t)BQ * SQ * DQ * 2;  // 8 MB per fp16 tensor
  char* wsb = (char*)d_ws;
  short* Qb = (short*)(wsb);
  short* Kb = (short*)(wsb + SEG);
  short* Vt = (short*)(wsb + 2 * SEG);
  float* Wc = (float*)(wsb + 3 * SEG);  // 257 floats

  dim3 g1(256, 12);
  qkv_kernel<<<g1, 256, 0, stream>>>(x, Wqkv, bqkv, Qb, Kb, Vt);
  wcomb_kernel<<<1, 256, 0, stream>>>(Wproj, bproj, Wfc, bfc, Wc);
  attn_kernel<<<256, 512, 0, stream>>>(Qb, Kb, Vt, Wc, out);
}

// Round 7
// 122.397 us; speedup vs baseline: 9.9709x; 9.9709x over previous
//
#include <hip/hip_runtime.h>
#include <hip/hip_bf16.h>

#define BQ 4
#define SQ 4096
#define DQ 256
#define N3 768
#define KBLK 64
#define NITER (SQ / KBLK)

typedef __attribute__((ext_vector_type(8))) _Float16 f16x8;
typedef __attribute__((ext_vector_type(4))) float f32x4;
typedef __attribute__((ext_vector_type(4))) unsigned int u32x4;

__device__ __forceinline__ short f2h(float f) {
  _Float16 h = (_Float16)f;
  union { _Float16 h; short s; } v; v.h = h;
  return v.s;
}

__device__ __forceinline__ void gload16(const void* g, void* lds) {
  __builtin_amdgcn_global_load_lds(
      (const __attribute__((address_space(1))) unsigned int*)g,
      (__attribute__((address_space(3))) unsigned int*)lds, 16, 0, 0);
}

// ---------------- Wcomb = Wproj @ Wfc ; c0 = bproj @ Wfc + bfc ----------------
__global__ void wcomb_kernel(const float* __restrict__ Wproj,
                             const float* __restrict__ bproj,
                             const float* __restrict__ Wfc,
                             const float* __restrict__ bfc,
                             float* __restrict__ Wc) {
  __shared__ float wf[256];
  const int t = threadIdx.x;
  wf[t] = Wfc[t];
  __syncthreads();
  float acc = 0.f;
  for (int j = 0; j < 256; ++j) acc += Wproj[(size_t)t * 256 + j] * wf[j];
  Wc[t] = acc;
  if (t == 0) {
    float c = bfc[0];
    for (int j = 0; j < 256; ++j) c += bproj[j] * wf[j];
    Wc[256] = c;
  }
}

// ---------------- QKV projection ----------------
// Writes Q,K row-major fp16 [B*S][256]. V columns are folded into
// u_part[vb][row] = sum_{64 cols of this block} (v+bias)*Wc[col]  (f32).
__global__ __launch_bounds__(256) void qkv_kernel(
    const float* __restrict__ x, const float* __restrict__ Wqkv,
    const float* __restrict__ bqkv, const float* __restrict__ Wc,
    short* __restrict__ Qb, short* __restrict__ Kb,
    float* __restrict__ u_part) {
  __shared__ short As[64][72];
  __shared__ short Ws[64][72];
  const int t = threadIdx.x;
  const int l = t & 63, w = t >> 6;
  const int lr = l & 15, lg = l >> 4;
  const int Mbase = blockIdx.x * 64;
  const int Nbase = blockIdx.y * 64;

  f32x4 acc[4] = {};
  for (int kit = 0; kit < 4; ++kit) {
    const int k0 = kit * 64;
    {
      const int m = t >> 2, kc = (t & 3) * 16;
      const float* src = x + (size_t)(Mbase + m) * DQ + k0 + kc;
      short tmp[16];
#pragma unroll
      for (int i = 0; i < 16; ++i) tmp[i] = f2h(src[i]);
      *(u32x4*)&As[m][kc] = *(u32x4*)&tmp[0];
      *(u32x4*)&As[m][kc + 8] = *(u32x4*)&tmp[8];
    }
    {
      const int n = t & 63, kc2 = (t >> 6) * 16;
      short tmp[16];
#pragma unroll
      for (int i = 0; i < 16; ++i)
        tmp[i] = f2h(Wqkv[(size_t)(k0 + kc2 + i) * N3 + Nbase + n]);
      *(u32x4*)&Ws[n][kc2] = *(u32x4*)&tmp[0];
      *(u32x4*)&Ws[n][kc2 + 8] = *(u32x4*)&tmp[8];
    }
    __syncthreads();
#pragma unroll
    for (int kk = 0; kk < 2; ++kk) {
      f16x8 af = *(f16x8*)&As[w * 16 + lr][kk * 32 + lg * 8];
#pragma unroll
      for (int nf = 0; nf < 4; ++nf) {
        f16x8 bfr = *(f16x8*)&Ws[nf * 16 + lr][kk * 32 + lg * 8];
        acc[nf] = __builtin_amdgcn_mfma_f32_16x16x32_f16(af, bfr, acc[nf], 0, 0, 0);
      }
    }
    __syncthreads();
  }

  if (Nbase < 512) {
    // Q / K epilogue: bias, cast fp16, store row-major
#pragma unroll
    for (int nf = 0; nf < 4; ++nf) {
      const int col = Nbase + nf * 16 + lr;
      const float bias = bqkv[col];
#pragma unroll
      for (int r = 0; r < 4; ++r) {
        const int row = Mbase + w * 16 + lg * 4 + r;
        const short sv = f2h(acc[nf][r] + bias);
        if (col < 256) Qb[(size_t)row * DQ + col] = sv;
        else           Kb[(size_t)row * DQ + (col - 256)] = sv;
      }
    }
  } else {
    // V columns: partial u = sum_cols (v + bias) * Wc[col-512]
    float partial[4] = {0.f, 0.f, 0.f, 0.f};
#pragma unroll
    for (int nf = 0; nf < 4; ++nf) {
      const int col = Nbase + nf * 16 + lr;
      const float bias = bqkv[col];
      const float wcv = Wc[col - 512];
#pragma unroll
      for (int r = 0; r < 4; ++r) partial[r] += (acc[nf][r] + bias) * wcv;
    }
#pragma unroll
    for (int mask = 1; mask <= 8; mask <<= 1)
#pragma unroll
      for (int r = 0; r < 4; ++r) partial[r] += __shfl_xor(partial[r], mask, 64);
    if (lr == 0) {
      const int vb = (Nbase - 512) >> 6;  // 0..3
#pragma unroll
      for (int r = 0; r < 4; ++r)
        u_part[(size_t)vb * (BQ * SQ) + Mbase + w * 16 + lg * 4 + r] = partial[r];
    }
  }
}

// ---------------- u = sum of 4 partials ----------------
__global__ void uvec_kernel(const float* __restrict__ up, float* __restrict__ u) {
  const int i = blockIdx.x * 256 + threadIdx.x;
  u[i] = up[i] + up[BQ * SQ + i] + up[2 * BQ * SQ + i] + up[3 * BQ * SQ + i];
}

// ---------------- Flash attention (QK^T + weighted u-sum) ----------------
// grid 512, 256 threads (4 waves). Block = 32 q-rows; wave w = 16-key quarter.
// Swapped QK^T: mfma(K,Q) -> lane holds S^T[key=lg*4+r][qrow=mm*16+lr].
// out[row] = (sum_k exp(s-m) * u[k]) / (sum_k exp(s-m)) + c0.
__global__ __launch_bounds__(256, 2) void attn_kernel(
    const short* __restrict__ Qb, const short* __restrict__ Kb,
    const float* __restrict__ u, const float* __restrict__ Wc,
    float* __restrict__ out) {
  __shared__ short Ks[2][64][256];  // [buf][key][d], XOR-swizzled chunks
  __shared__ float Mrg[4][32][3];   // [h][row]{m,den,num}

  const int t = threadIdx.x;
  const int l = t & 63, w = t >> 6;  // w = key-quarter h
  const int lr = l & 15, lg = l >> 4;
  const int bid = blockIdx.x;
  const int b = bid & 3;
  const int qbase = (bid >> 2) * 32;

  const short* kbase = Kb + (size_t)b * SQ * DQ;
  const float* ubase = u + (size_t)b * SQ;

  // Q fragments (B-operand): qrow = mm*16+lr, d = kk*32 + lg*8 + j
  f16x8 qf[2][8];
#pragma unroll
  for (int mm = 0; mm < 2; ++mm) {
    const short* qptr = Qb + (size_t)(b * SQ + qbase + mm * 16 + lr) * DQ;
#pragma unroll
    for (int kk = 0; kk < 8; ++kk)
      qf[mm][kk] = *(const f16x8*)(qptr + kk * 32 + lg * 8);
  }

  // K: LDS chunk c of row kr holds global chunk c^(kr&7)  (16B chunks)
#define STAGE(BUF, KB)                                                      \
  {                                                                         \
    _Pragma("unroll") for (int i = 0; i < 8; ++i) {                         \
      const int kr = w * 16 + i * 2 + (l >> 5);                             \
      const int gc = (l & 31) ^ (kr & 7);                                   \
      gload16(kbase + (size_t)((KB)*64 + kr) * DQ + gc * 8,                 \
              &Ks[BUF][w * 16 + i * 2][0]);                                 \
    }                                                                       \
  }

  float m_run[2] = {-1e30f, -1e30f};
  float num[2] = {0.f, 0.f}, den[2] = {0.f, 0.f};

  STAGE(0, 0);
  __syncthreads();

  for (int kb = 0; kb < NITER; ++kb) {
    const int cur = kb & 1;
    if (kb + 1 < NITER) STAGE(cur ^ 1, kb + 1);

    // u values for this lane's 4 keys (same for both mm)
    const f32x4 uv = *(const f32x4*)(ubase + kb * 64 + w * 16 + lg * 4);

    // S^T = K Q^T on this wave's 16 keys (4 independent MFMA chains)
    const char* kR = (const char*)&Ks[cur][w * 16 + lr][0];
    f32x4 sA[2] = {}, sB[2] = {};
#pragma unroll
    for (int kk = 0; kk < 4; ++kk) {
      f16x8 kf = *(const f16x8*)(kR + (((4 * kk + lg) ^ (lr & 7)) << 4));
      sA[0] = __builtin_amdgcn_mfma_f32_16x16x32_f16(kf, qf[0][kk], sA[0], 0, 0, 0);
      sA[1] = __builtin_amdgcn_mfma_f32_16x16x32_f16(kf, qf[1][kk], sA[1], 0, 0, 0);
    }
#pragma unroll
    for (int kk = 4; kk < 8; ++kk) {
      f16x8 kf = *(const f16x8*)(kR + (((4 * kk + lg) ^ (lr & 7)) << 4));
      sB[0] = __builtin_amdgcn_mfma_f32_16x16x32_f16(kf, qf[0][kk], sB[0], 0, 0, 0);
      sB[1] = __builtin_amdgcn_mfma_f32_16x16x32_f16(kf, qf[1][kk], sB[1], 0, 0, 0);
    }
    f32x4 s[2];
#pragma unroll
    for (int mm = 0; mm < 2; ++mm)
#pragma unroll
      for (int r = 0; r < 4; ++r) s[mm][r] = sA[mm][r] + sB[mm][r];

    // defer-max online softmax; common path has zero cross-lane ops
    bool over = false;
#pragma unroll
    for (int mm = 0; mm < 2; ++mm)
#pragma unroll
      for (int r = 0; r < 4; ++r) over = over || (s[mm][r] > m_run[mm] + 8.f);
    if (__any(over)) {
#pragma unroll
      for (int mm = 0; mm < 2; ++mm) {
        float mt = fmaxf(fmaxf(s[mm][0], s[mm][1]), fmaxf(s[mm][2], s[mm][3]));
        mt = fmaxf(mt, __shfl_xor(mt, 16, 64));
        mt = fmaxf(mt, __shfl_xor(mt, 32, 64));
        const float mn = fmaxf(m_run[mm], mt);
        const float sc = __expf(m_run[mm] - mn);
        m_run[mm] = mn;
        num[mm] *= sc;
        den[mm] *= sc;
      }
    }
#pragma unroll
    for (int mm = 0; mm < 2; ++mm)
#pragma unroll
      for (int r = 0; r < 4; ++r) {
        const float p = __expf(s[mm][r] - m_run[mm]);  // <= e^8
        den[mm] += p;
        num[mm] += p * uv[r];
      }
    __syncthreads();  // next tile landed (vmcnt drain) + reads of cur done
  }

  // reduce per-lane partials over the lg axis (keys)
#pragma unroll
  for (int mm = 0; mm < 2; ++mm) {
    num[mm] += __shfl_xor(num[mm], 16, 64);
    num[mm] += __shfl_xor(num[mm], 32, 64);
    den[mm] += __shfl_xor(den[mm], 16, 64);
    den[mm] += __shfl_xor(den[mm], 32, 64);
  }
  if (lg == 0) {
#pragma unroll
    for (int mm = 0; mm < 2; ++mm) {
      Mrg[w][mm * 16 + lr][0] = m_run[mm];
      Mrg[w][mm * 16 + lr][1] = den[mm];
      Mrg[w][mm * 16 + lr][2] = num[mm];
    }
  }
  __syncthreads();

  if (t < 32) {
    float M = Mrg[0][t][0];
#pragma unroll
    for (int hh = 1; hh < 4; ++hh) M = fmaxf(M, Mrg[hh][t][0]);
    float dt = 0.f, nt = 0.f;
#pragma unroll
    for (int hh = 0; hh < 4; ++hh) {
      const float e = __expf(Mrg[hh][t][0] - M);
      dt += e * Mrg[hh][t][1];
      nt += e * Mrg[hh][t][2];
    }
    out[(size_t)b * SQ + qbase + t] = nt / dt + Wc[256];
  }
#undef STAGE
}

// ---------------- launch ----------------
extern "C" void kernel_launch(void* const* d_in, const int* in_sizes, int n_in,
                              void* d_out, int out_size, void* d_ws, size_t ws_size,
                              hipStream_t stream) {
  const float* x     = (const float*)d_in[0];
  const float* Wqkv  = (const float*)d_in[1];
  const float* bqkv  = (const float*)d_in[2];
  const float* Wproj = (const float*)d_in[3];
  const float* bproj = (const float*)d_in[4];
  const float* Wfc   = (const float*)d_in[5];
  const float* bfc   = (const float*)d_in[6];
  float* out = (float*)d_out;

  const size_t SEG = (size_t)BQ * SQ * DQ * 2;  // 8 MB per fp16 tensor
  char* wsb = (char*)d_ws;
  short* Qb     = (short*)(wsb);
  short* Kb     = (short*)(wsb + SEG);
  float* Wc     = (float*)(wsb + 2 * SEG);                    // 257 floats
  float* u_part = (float*)(wsb + 2 * SEG + 4096);             // 4*16384 floats
  float* u      = (float*)(wsb + 2 * SEG + 4096 + 4 * BQ * SQ * 4);  // 16384

  wcomb_kernel<<<1, 256, 0, stream>>>(Wproj, bproj, Wfc, bfc, Wc);
  dim3 g1(256, 12);
  qkv_kernel<<<g1, 256, 0, stream>>>(x, Wqkv, bqkv, Wc, Qb, Kb, u_part);
  uvec_kernel<<<BQ * SQ / 256, 256, 0, stream>>>(u_part, u);
  attn_kernel<<<512, 256, 0, stream>>>(Qb, Kb, u, Wc, out);
}